// Round 10
// baseline (365.110 us; speedup 1.0000x reference)
//
#include <hip/hip_runtime.h>
#include <cstdint>

typedef unsigned short u16;
typedef __attribute__((ext_vector_type(8))) short short8;   // bf16x8 MFMA frag
typedef __attribute__((ext_vector_type(4))) short short4v;  // bf16x4
typedef __attribute__((ext_vector_type(4))) float f32x4;    // fp32x4 accumulator

#define SEQ     2048
#define NHEADS  32
#define NKV     8
#define HD      64
#define DM      2048
#define MROWS   4096   // BATCH * SEQ
#define KVSTR   1024   // fused KV row stride (8 K-heads | 8 V-heads)
#define PSTR    88     // Ps row stride (u16): 176B, 16B-aligned, 2-way banks

__device__ __forceinline__ float b2f(unsigned int u) {
    return __builtin_bit_cast(float, u << 16);
}
__device__ __forceinline__ u16 f2b(float f) {
    unsigned int u = __builtin_bit_cast(unsigned int, f);
    return (u16)((u + 0x7fffu + ((u >> 16) & 1u)) >> 16);   // RNE
}
// packed f32x2 -> bf16x2 (HW RNE). No builtin on gfx950 (m240) — inline asm.
__device__ __forceinline__ unsigned int cvt_pk_bf16(float lo, float hi) {
    unsigned int r;
    asm("v_cvt_pk_bf16_f32 %0, %1, %2" : "=v"(r) : "v"(lo), "v"(hi));
    return r;
}

// ---- DPP 16-lane reductions (VALU pipe — round-4 win, keep)
__device__ __forceinline__ float dpp_red_max16(float x) {
    int v = __builtin_bit_cast(int, x);
    x = fmaxf(x, __builtin_bit_cast(float,
        __builtin_amdgcn_update_dpp(v, v, 0xB1, 0xF, 0xF, true)));
    v = __builtin_bit_cast(int, x);
    x = fmaxf(x, __builtin_bit_cast(float,
        __builtin_amdgcn_update_dpp(v, v, 0x4E, 0xF, 0xF, true)));
    v = __builtin_bit_cast(int, x);
    x = fmaxf(x, __builtin_bit_cast(float,
        __builtin_amdgcn_update_dpp(v, v, 0x141, 0xF, 0xF, true)));
    v = __builtin_bit_cast(int, x);
    x = fmaxf(x, __builtin_bit_cast(float,
        __builtin_amdgcn_update_dpp(v, v, 0x140, 0xF, 0xF, true)));
    return x;
}
__device__ __forceinline__ float dpp_red_sum16(float x) {
    int v = __builtin_bit_cast(int, x);
    x = x + __builtin_bit_cast(float,
        __builtin_amdgcn_update_dpp(v, v, 0xB1, 0xF, 0xF, true));
    v = __builtin_bit_cast(int, x);
    x = x + __builtin_bit_cast(float,
        __builtin_amdgcn_update_dpp(v, v, 0x4E, 0xF, 0xF, true));
    v = __builtin_bit_cast(int, x);
    x = x + __builtin_bit_cast(float,
        __builtin_amdgcn_update_dpp(v, v, 0x141, 0xF, 0xF, true));
    v = __builtin_bit_cast(int, x);
    x = x + __builtin_bit_cast(float,
        __builtin_amdgcn_update_dpp(v, v, 0x140, 0xF, 0xF, true));
    return x;
}

// async global->LDS, 16B per lane; LDS dest = WAVE-UNIFORM base + lane*16;
// global source is per-lane (enables source-side swizzle).
#define GLOAD_LDS16(g, l)                                              \
    __builtin_amdgcn_global_load_lds(                                  \
        (const __attribute__((address_space(1))) void*)(g),            \
        (__attribute__((address_space(3))) void*)(l), 16, 0, 0)

// ------------------------------------------------------------- f32 -> bf16
__global__ __launch_bounds__(256) void cvt_f32_bf16(
    const float* __restrict__ in, u16* __restrict__ out, int n4) {
    int i = blockIdx.x * 256 + threadIdx.x;
    if (i < n4) {
        float4 v = ((const float4*)in)[i];
        ushort4 o;
        o.x = f2b(v.x); o.y = f2b(v.y); o.z = f2b(v.z); o.w = f2b(v.w);
        ((ushort4*)out)[i] = o;
    }
}

// ------------------------------------------------------------- RoPE tables
__global__ __launch_bounds__(256) void rope_table_kernel(
    float* __restrict__ cosT, float* __restrict__ sinT) {
    int idx = blockIdx.x * 256 + threadIdx.x;     // 65536 = 2048*32
    int s  = idx >> 5;
    int dl = idx & 31;
    float inv_freq = exp2f((float)dl * -0.41524101186092025f); // 10000^(-dl/32)
    float ang = (float)s * inv_freq;
    float sn, cs;
    sincosf(ang, &sn, &cs);                        // accurate (range-reduced)
    cosT[idx] = cs;
    sinT[idx] = sn;
}

// ------------------------------------------------- transpose + downcast
__global__ __launch_bounds__(256) void transpose_f32_bf16(
    const float* __restrict__ in, u16* __restrict__ out, int K, int N) {
    __shared__ float tile[32][33];
    int n0 = blockIdx.x * 32, k0 = blockIdx.y * 32;
    int tx = threadIdx.x, ty = threadIdx.y;   // 32 x 8
    for (int r = ty; r < 32; r += 8)
        tile[r][tx] = in[(size_t)(k0 + r) * N + n0 + tx];
    __syncthreads();
    for (int r = ty; r < 32; r += 8)
        out[(size_t)(n0 + r) * K + k0 + tx] = f2b(tile[tx][r]);
}

// ------------------------------------------------------- GEMM core macro
// Depth-3 ring, stage AFTER wait+barrier (round-9 proven schedule; the
// round-7/8 stage-before-barrier variant raced: staging tile s+2 writes
// tile s-1's buffer while other waves may still read it). Wait ladder:
// top of step s has tiles s,s+1 outstanding (8 loads) -> vmcnt(4);
// s==NT-1 -> vmcnt(0). Never drains mid-loop. Slot-swizzled LDS for
// conflict-free ds_read_b128 (inverse swizzle pre-applied on per-lane
// GLOBAL source; LDS dest linear). XCD-chunked bijective block swizzle
// (T1); s_setprio around MFMA (T5).
#define GEMM_BODY(Aptr, BTptr, Kdim)                                        \
    __shared__ __align__(16) u16 rA[3][4096];                               \
    __shared__ __align__(16) u16 rB[3][4096];                               \
    const int tid  = threadIdx.x;                                           \
    const int wid  = tid >> 6;                                              \
    const int lane = tid & 63;                                              \
    const int quad = lane >> 4;                                             \
    const int l16  = lane & 15;                                             \
    const int nwg  = gridDim.x * gridDim.y;                                 \
    const int fid  = blockIdx.y * gridDim.x + blockIdx.x;                   \
    const int swz  = (fid & 7) * (nwg >> 3) + (fid >> 3);                   \
    const int rowBase = (swz / gridDim.x) * 128;                            \
    const int colBase = (swz % gridDim.x) * 128;                            \
    const int wr = (wid >> 1) * 64;                                         \
    const int wc = (wid & 1) * 64;                                          \
    size_t sAoff[2], sBoff[2];                                              \
    int ldOff[2];                                                           \
    _Pragma("unroll")                                                       \
    for (int j = 0; j < 2; ++j) {                                           \
        const int p = j * 256 + tid;      /* phys 16B slot this thread fills */ \
        const int q = p >> 3;                                               \
        const int u = (p & 7) ^ (q & 7);  /* inverse swizzle */             \
        const int r = (q << 1) | (u >> 2);                                  \
        const int sc = (u & 3) * 8;       /* k-subgroup (elements) */       \
        sAoff[j] = (size_t)(rowBase + r) * (Kdim) + sc;                     \
        sBoff[j] = (size_t)(colBase + r) * (Kdim) + sc;                     \
        ldOff[j] = (j * 256 + (wid << 6)) * 8;   /* wave-uniform, u16 units */ \
    }                                                                       \
    int aOff[4], bOff[4];                 /* swizzled read offsets (u16) */ \
    _Pragma("unroll")                                                       \
    for (int mi = 0; mi < 4; ++mi) {                                        \
        const int ra = wr + mi * 16 + l16;                                  \
        const int qa = ra >> 1;                                             \
        const int ua = ((ra & 1) << 2) | quad;                              \
        aOff[mi] = (qa * 8 + (ua ^ (qa & 7))) * 8;                          \
        const int rb = wc + mi * 16 + l16;                                  \
        const int qb = rb >> 1;                                             \
        const int ub = ((rb & 1) << 2) | quad;                              \
        bOff[mi] = (qb * 8 + (ub ^ (qb & 7))) * 8;                          \
    }                                                                       \
    f32x4 acc[4][4] = {};                                                   \
    const int NT = (Kdim) / 32;                                             \
    _Pragma("unroll")                                                       \
    for (int st = 0; st < 2; ++st) {      /* prologue: stage tiles 0,1 */   \
        _Pragma("unroll")                                                   \
        for (int j = 0; j < 2; ++j) {                                       \
            GLOAD_LDS16(Aptr  + sAoff[j] + st * 32, &rA[st][ldOff[j]]);     \
            GLOAD_LDS16(BTptr + sBoff[j] + st * 32, &rB[st][ldOff[j]]);     \
        }                                                                   \
    }                                                                       \
    int bs = 0;                           /* s % 3, tracked incrementally */ \
    for (int s = 0; s < NT; ++s) {                                          \
        if (s < NT - 1)                                                     \
            asm volatile("s_waitcnt vmcnt(4)\n\ts_barrier" ::: "memory");   \
        else                                                                \
            asm volatile("s_waitcnt vmcnt(0)\n\ts_barrier" ::: "memory");   \
        const u16* Ab = rA[bs];                                             \
        const u16* Bb = rB[bs];                                             \
        short8 a[4], b[4];                                                  \
        _Pragma("unroll")                                                   \
        for (int mi = 0; mi < 4; ++mi) a[mi] = *(const short8*)&Ab[aOff[mi]]; \
        _Pragma("unroll")                                                   \
        for (int ni = 0; ni < 4; ++ni) b[ni] = *(const short8*)&Bb[bOff[ni]]; \
        if (s + 2 < NT) {                 /* stage s+2 (AFTER barrier) */   \
            const int bi = bs == 0 ? 2 : bs - 1;   /* (s+2)%3 */            \
            const int kk = (s + 2) * 32;                                    \
            _Pragma("unroll")                                               \
            for (int j = 0; j < 2; ++j) {                                   \
                GLOAD_LDS16(Aptr  + sAoff[j] + kk, &rA[bi][ldOff[j]]);      \
                GLOAD_LDS16(BTptr + sBoff[j] + kk, &rB[bi][ldOff[j]]);      \
            }                                                               \
        }                                                                   \
        __builtin_amdgcn_s_setprio(1);                                      \
        _Pragma("unroll")                                                   \
        for (int mi = 0; mi < 4; ++mi)                                      \
            _Pragma("unroll")                                               \
            for (int ni = 0; ni < 4; ++ni)                                  \
                acc[mi][ni] = __builtin_amdgcn_mfma_f32_16x16x32_bf16(      \
                    a[mi], b[ni], acc[mi][ni], 0, 0, 0);                    \
        __builtin_amdgcn_s_setprio(0);                                      \
        bs = bs == 2 ? 0 : bs + 1;                                          \
    }                                                                       \
    const int wRow = rowBase + wr;                                          \
    const int wCol = colBase + wc;

// ------------------------------------------------------- fused QKV GEMM
// ROUND-10: Q pre-scale is now (1/8)*log2(e) — softmax runs in log2
// domain (exp2f = bare v_exp_f32, no hidden v_mul). Applied in f32 before
// the same single bf16 rounding -> mathematically equivalent.
__global__ __launch_bounds__(256, 3) void gemm_qkv(
    const u16* __restrict__ A, const u16* __restrict__ BT,
    u16* __restrict__ Qb, u16* __restrict__ KVb,
    const float* __restrict__ cosT, const float* __restrict__ sinT) {
    GEMM_BODY(A, BT, DM)

    u16* dst;
    int dstride, dcol;
    float scale;
    bool doRope;
    if (wCol < 2048)      { dst = Qb;  dstride = 2048; dcol = wCol;
                            scale = 0.18033688011112042f; doRope = true;  } // log2e/8
    else if (wCol < 2560) { dst = KVb; dstride = 1024; dcol = wCol - 2048; scale = 1.0f; doRope = true;  }
    else                  { dst = KVb; dstride = 1024; dcol = wCol - 2048; scale = 1.0f; doRope = false; }

#pragma unroll
    for (int mi = 0; mi < 4; ++mi) {
#pragma unroll
        for (int r = 0; r < 4; ++r) {
            const int R = wRow + mi * 16 + quad * 4 + r;
            u16* crow = dst + (size_t)R * dstride + dcol;
            if (doRope) {
                const int s = R & (SEQ - 1);
#pragma unroll
                for (int ni = 0; ni < 2; ++ni) {
                    const int dl = ni * 16 + l16;           // 0..31
                    float lo = acc[mi][ni][r];
                    float hi = acc[mi][ni + 2][r];
                    float cs = cosT[s * 32 + dl];
                    float sn = sinT[s * 32 + dl];
                    crow[dl]      = f2b((lo * cs - hi * sn) * scale);
                    crow[dl + 32] = f2b((hi * cs + lo * sn) * scale);
                }
            } else {
#pragma unroll
                for (int ni = 0; ni < 4; ++ni)
                    crow[ni * 16 + l16] = f2b(acc[mi][ni][r]);
            }
        }
    }
}

// ------------------------------------------------------- output GEMM (f32)
__global__ __launch_bounds__(256, 3) void gemm_out(
    const u16* __restrict__ A, const u16* __restrict__ BT,
    float* __restrict__ C32) {
    GEMM_BODY(A, BT, DM)
#pragma unroll
    for (int mi = 0; mi < 4; ++mi) {
#pragma unroll
        for (int r = 0; r < 4; ++r) {
            const int R = wRow + mi * 16 + quad * 4 + r;
            float* crow = C32 + (size_t)R * DM + wCol;
#pragma unroll
            for (int ni = 0; ni < 4; ++ni)
                crow[ni * 16 + l16] = acc[mi][ni][r];
        }
    }
}

// ------------------------------------------------------- flash attention
// 4 waves x 32 q-rows/wave (r9). ROUND-10: VALU diet — r9 showed halving
// K/V LDS reads changed nothing (BANK_CONFLICT 5.57M->3.34M, dur flat),
// refuting the LDS-throughput model; per-tile budget is dominated by
// softmax VALU inst count (~400/wave-tile: 32 __expf = mul+exp each,
// ~128 inst of manual f2b RNE, 64 DPP+ops). Changes (schedule-neutral):
//  (a) log2-domain: S already scaled by log2e in GEMM -> exp2f everywhere
//      (bare v_exp_f32); defer threshold 8 nats -> 11.54 bits.
//  (b) P conversion via v_cvt_pk_bf16_f32 (16 packed + 16 shr replaces
//      ~128 inst of manual f2b).
// Split-K (r3) + DPP softmax (r4) + T13 defer-max retained.
__global__ __launch_bounds__(256, 3) void flash_attn(
    const u16* __restrict__ Q, const u16* __restrict__ KV,
    u16* __restrict__ Yb, float* __restrict__ PoA,
    float* __restrict__ Ml) {
    __shared__ __align__(16) u16 Ks[64 * 64];         // 8 KB, XOR-swizzled
    __shared__ __align__(16) u16 Vt[64 * 72];         // 9 KB, [dim][key]
    __shared__ __align__(16) u16 Ps[4 * 32 * PSTR];   // 22 KB

    const int p   = blockIdx.x >> 1;    // pair 0..7
    const int sh  = blockIdx.x & 1;     // key-half 0/1
    const int h   = blockIdx.y;
    const int b   = blockIdx.z;
    const int kvh = h >> 2;
    const int tid  = threadIdx.x;
    const int wid  = tid >> 6;          // 0..3
    const int lane = tid & 63;
    const int quad = lane >> 4;
    const int l16  = lane & 15;

    const u16* Kg = KV + (size_t)b * SEQ * KVSTR + kvh * HD;
    const u16* Vg = Kg + 512;
    u16* Psw = Ps + wid * 32 * PSTR;

    // staging coords (256 threads)
    const int kKey = tid >> 2;          // key row 0..63
    const int kC0  = (tid & 3) * 2;     // two 16B chunks: kC0, kC0+1
    const int vkp  = tid & 31;          // V key pair 2vkp, 2vkp+1
    const int vd0  = (tid >> 5) * 8;    // 8 dims

    for (int ph = 0; ph < 2; ++ph) {
        const int qt = ph ? (15 - p) : p;
        const int hc = ph ? (16 - p) : (p + 1);   // tiles in each key-half
        const int tS = sh * hc;                    // first key-tile index
        const int rowBaseW = qt * 128 + wid * 32;

        // --- preload Q A-frags (pre-scaled log2e/8), 2 row-tiles x 2 k-slices
        short8 qf[2][2];
#pragma unroll
        for (int rt = 0; rt < 2; ++rt)
#pragma unroll
            for (int ks = 0; ks < 2; ++ks)
                qf[rt][ks] = *(const short8*)&Q[
                    (size_t)(b * SEQ + rowBaseW + rt * 16 + l16) * (NHEADS * HD)
                    + h * HD + ks * 32 + quad * 8];

        f32x4 o[2][4] = {};
        float mi[8], li[8];
#pragma unroll
        for (int i = 0; i < 8; ++i) { mi[i] = -3e38f; li[i] = 0.f; }

        // --- prefetch first tile of this phase's range
        const size_t jF = (size_t)tS * 64;
        short8 kreg0 = *(const short8*)&Kg[(jF + kKey) * KVSTR + kC0 * 8];
        short8 kreg1 = *(const short8*)&Kg[(jF + kKey) * KVSTR + kC0 * 8 + 8];
        short8 vA = *(const short8*)&Vg[(jF + 2 * vkp)     * KVSTR + vd0];
        short8 vB = *(const short8*)&Vg[(jF + 2 * vkp + 1) * KVSTR + vd0];

        for (int tt = 0; tt < hc; ++tt) {
            const int j0 = (tS + tt) * 64;
            __syncthreads();   // previous tile's LDS reads done

            // --- write staged K (XOR-swizzled 16B chunks, 2 per thread)
            *(short8*)&Ks[kKey * 64 + (((kC0)     ^ (kKey & 7)) * 8)] = kreg0;
            *(short8*)&Ks[kKey * 64 + (((kC0 + 1) ^ (kKey & 7)) * 8)] = kreg1;
            // --- write staged V as packed key-pairs (8 x b32, conflict-free)
#pragma unroll
            for (int i = 0; i < 8; ++i) {
                unsigned int w = (unsigned int)(u16)vA[i]
                               | ((unsigned int)(u16)vB[i] << 16);
                ((unsigned int*)Vt)[(vd0 + i) * 36 + vkp] = w;
            }
            __syncthreads();

            // --- prefetch tile tt+1 (overlaps with compute below)
            if (tt + 1 < hc) {
                const size_t jn = (size_t)(j0 + 64);
                kreg0 = *(const short8*)&Kg[(jn + kKey) * KVSTR + kC0 * 8];
                kreg1 = *(const short8*)&Kg[(jn + kKey) * KVSTR + kC0 * 8 + 8];
                vA = *(const short8*)&Vg[(jn + 2 * vkp)     * KVSTR + vd0];
                vB = *(const short8*)&Vg[(jn + 2 * vkp + 1) * KVSTR + vd0];
            }

            // --- S = Q @ K^T (16 MFMA; each bk feeds both row-tiles)
            f32x4 s[2][4] = {};
#pragma unroll
            for (int ks = 0; ks < 2; ++ks)
#pragma unroll
                for (int ct = 0; ct < 4; ++ct) {
                    int key = ct * 16 + l16;
                    int cc  = (ks * 4 + quad) ^ (key & 7);
                    short8 bk = *(const short8*)&Ks[key * 64 + cc * 8];
                    s[0][ct] = __builtin_amdgcn_mfma_f32_16x16x32_bf16(
                        qf[0][ks], bk, s[0][ct], 0, 0, 0);
                    s[1][ct] = __builtin_amdgcn_mfma_f32_16x16x32_bf16(
                        qf[1][ks], bk, s[1][ct], 0, 0, 0);
                }

            // --- causal mask (per row-tile gate)
#pragma unroll
            for (int rt = 0; rt < 2; ++rt) {
                const int rB = rowBaseW + rt * 16;
                if (j0 + 63 > rB) {
#pragma unroll
                    for (int ct = 0; ct < 4; ++ct)
#pragma unroll
                        for (int r = 0; r < 4; ++r) {
                            int R = rB + quad * 4 + r;
                            int J = j0 + ct * 16 + l16;
                            if (J > R) s[rt][ct][r] = -3e38f;
                        }
                }
            }

            // --- online softmax, log2 domain (DPP reduce) + T13 defer-max
#pragma unroll
            for (int rt = 0; rt < 2; ++rt)
#pragma unroll
                for (int r = 0; r < 4; ++r) {
                    const int ix = rt * 4 + r;
                    float rmax = fmaxf(fmaxf(s[rt][0][r], s[rt][1][r]),
                                       fmaxf(s[rt][2][r], s[rt][3][r]));
                    rmax = dpp_red_max16(rmax);
                    if (!__all(rmax <= mi[ix] + 11.54f)) {   // 8 nats in bits
                        float mnew  = fmaxf(mi[ix], rmax);
                        float alpha = exp2f(mi[ix] - mnew);
                        mi[ix] = mnew;
                        li[ix] *= alpha;
#pragma unroll
                        for (int ct = 0; ct < 4; ++ct) o[rt][ct][r] *= alpha;
                    }
                    float rs = 0.f;
#pragma unroll
                    for (int ct = 0; ct < 4; ++ct) {
                        float pv = exp2f(s[rt][ct][r] - mi[ix]);
                        s[rt][ct][r] = pv;
                        rs += pv;
                    }
                    rs = dpp_red_sum16(rs);
                    li[ix] += rs;
                }

            // --- P -> bf16 via packed cvt, C-layout -> LDS (wave-private)
#pragma unroll
            for (int rt = 0; rt < 2; ++rt)
#pragma unroll
                for (int ct = 0; ct < 4; ++ct)
#pragma unroll
                    for (int rp = 0; rp < 2; ++rp) {
                        unsigned int pk = cvt_pk_bf16(s[rt][ct][2 * rp],
                                                      s[rt][ct][2 * rp + 1]);
                        const int row = rt * 16 + quad * 4 + 2 * rp;
                        Psw[row * PSTR + ct * 16 + l16]       = (u16)pk;
                        Psw[(row + 1) * PSTR + ct * 16 + l16] = (u16)(pk >> 16);
                    }

            // --- O += P @ V (16 MFMA; each vbf feeds both row-tiles)
#pragma unroll
            for (int ks = 0; ks < 2; ++ks) {
                short8 pa0 = *(const short8*)&Psw[l16 * PSTR + ks * 32 + quad * 8];
                short8 pa1 = *(const short8*)&Psw[(16 + l16) * PSTR + ks * 32 + quad * 8];
#pragma unroll
                for (int ct = 0; ct < 4; ++ct) {
                    short8 vbf = *(const short8*)&Vt[(ct * 16 + l16) * 72 + ks * 32 + quad * 8];
                    o[0][ct] = __builtin_amdgcn_mfma_f32_16x16x32_bf16(
                        pa0, vbf, o[0][ct], 0, 0, 0);
                    o[1][ct] = __builtin_amdgcn_mfma_f32_16x16x32_bf16(
                        pa1, vbf, o[1][ct], 0, 0, 0);
                }
            }
        }

        // --- write this phase's normalized partial + (m,l)  [m in log2 units]
        float rli[8];
#pragma unroll
        for (int i = 0; i < 8; ++i)
            rli[i] = li[i] > 0.f ? 1.0f / li[i] : 0.f;   // guard empty rows
        if (sh == 0) {
#pragma unroll
            for (int rt = 0; rt < 2; ++rt)
#pragma unroll
                for (int r = 0; r < 4; ++r) {
                    int R = rowBaseW + rt * 16 + quad * 4 + r;
                    float* arow = PoA + (size_t)(b * SEQ + R) * (NHEADS * HD) + h * HD;
#pragma unroll
                    for (int ct = 0; ct < 4; ++ct)
                        arow[ct * 16 + l16] = o[rt][ct][r] * rli[rt * 4 + r];
                }
        } else {
#pragma unroll
            for (int rt = 0; rt < 2; ++rt)
#pragma unroll
                for (int r = 0; r < 4; ++r) {
                    int R = rowBaseW + rt * 16 + quad * 4 + r;
                    u16* yrow = Yb + (size_t)(b * SEQ + R) * (NHEADS * HD) + h * HD;
#pragma unroll
                    for (int ct = 0; ct < 4; ++ct)
                        yrow[ct * 16 + l16] = f2b(o[rt][ct][r] * rli[rt * 4 + r]);
                }
        }
        if (l16 == 0) {
            float2* MlX = (float2*)Ml + (size_t)sh * 131072
                        + ((b * 32 + h) * 2048 + rowBaseW + quad * 4);
#pragma unroll
            for (int rt = 0; rt < 2; ++rt)
#pragma unroll
                for (int r = 0; r < 4; ++r)
                    MlX[rt * 16 + r] = make_float2(mi[rt * 4 + r], li[rt * 4 + r]);
        }
    }
}

// ------------------------------------------------------- split-K combine
// m-values are in LOG2 domain (round 10) -> exp2f weights.
__global__ __launch_bounds__(256) void combine_kernel(
    const float* __restrict__ PoA, const float* __restrict__ Ml,
    u16* __restrict__ Yb) {
    const size_t e = ((size_t)blockIdx.x * 256 + threadIdx.x) * 8;
    const int rowg = (int)(e >> 11);          // b*2048 + row
    const int c    = (int)(e & 2047);
    const int h    = c >> 6;
    const int bz   = rowg >> 11;
    const int row  = rowg & 2047;
    const int slot = ((bz * 32 + h) * 2048 + row) * 2;
    const float mA = Ml[slot],          lA = Ml[slot + 1];
    const float mB = Ml[262144 + slot], lB = Ml[262144 + slot + 1];
    const float m  = fmaxf(mA, mB);
    const float wA = lA * exp2f(mA - m);
    const float wB = lB * exp2f(mB - m);
    const float inv = 1.0f / (wA + wB);       // lA > 0 always
    const float a = wA * inv, bw = wB * inv;
    float4 A0 = *(const float4*)(PoA + e);
    float4 A1 = *(const float4*)(PoA + e + 4);
    short8 Bv = *(const short8*)(Yb + e);
    float av[8] = {A0.x, A0.y, A0.z, A0.w, A1.x, A1.y, A1.z, A1.w};
    u16 yo[8];
#pragma unroll
    for (int j = 0; j < 8; ++j)
        yo[j] = f2b(a * av[j] + bw * b2f((unsigned int)(u16)Bv[j]));
    *(short8*)(Yb + e) = *(short8*)yo;
}

// ---------------------------------------------------------------- launch
extern "C" void kernel_launch(void* const* d_in, const int* in_sizes, int n_in,
                              void* d_out, int out_size, void* d_ws, size_t ws_size,
                              hipStream_t stream) {
    const float* x  = (const float*)d_in[0];
    const float* Wq = (const float*)d_in[1];
    const float* Wk = (const float*)d_in[2];
    const float* Wv = (const float*)d_in[3];
    const float* Wo = (const float*)d_in[4];
    float* out = (float*)d_out;   // f32 output

    char* ws = (char*)d_ws;
    u16*  xb    = (u16*)(ws);                    // 16 MB  4096x2048 bf16
    u16*  WqkvT = (u16*)(ws + 16777216);         // 12 MB  3072x2048 (Wq|Wk|Wv)^T
    u16*  WoT   = (u16*)(ws + 29360128);         //  8 MB  2048x2048 [28,36) MB
    u16*  Qb    = (u16*)(ws + 37748736);         // 16 MB  (roped, pre-scaled log2e/8)
    u16*  KVb   = (u16*)(ws + 54525952);         //  8 MB  4096x1024 (K roped | V)
    u16*  Yb    = (u16*)(ws + 62914560);         // 16 MB  partial-B then final Y
    float* cosT = (float*)(ws + 79691776);       // 256 KB
    float* sinT = (float*)(ws + 79953920);       // 256 KB
    // flash-phase aliases (xb/WqkvT/WoT dead during attention):
    float* PoA  = (float*)(ws);                  // 32 MB f32 partial-A [0,32)
    float* Ml   = (float*)(ws + 33554432);       //  2 MB (m,l) x {A,B} [32,34)

    rope_table_kernel<<<dim3(65536 / 256), 256, 0, stream>>>(cosT, sinT);

    cvt_f32_bf16<<<dim3(MROWS * DM / 4 / 256), 256, 0, stream>>>(x, xb, MROWS * DM / 4);

    dim3 tb(32, 8);
    transpose_f32_bf16<<<dim3(2048/32, 2048/32), tb, 0, stream>>>(Wq, WqkvT, 2048, 2048);
    transpose_f32_bf16<<<dim3( 512/32, 2048/32), tb, 0, stream>>>(Wk, WqkvT + 2048 * 2048, 2048, 512);
    transpose_f32_bf16<<<dim3( 512/32, 2048/32), tb, 0, stream>>>(Wv, WqkvT + 2560 * 2048, 2048, 512);

    gemm_qkv<<<dim3(24, 32), 256, 0, stream>>>(xb, WqkvT, Qb, KVb, cosT, sinT);

    flash_attn<<<dim3(16, NHEADS, 2), 256, 0, stream>>>(Qb, KVb, Yb, PoA, Ml);

    combine_kernel<<<dim3(4096), 256, 0, stream>>>(PoA, Ml, Yb);

    // Wo transpose AFTER combine: WoT region [28,36) was reused for
    // PoA-tail + Ml during the attention phase (stream is serial).
    transpose_f32_bf16<<<dim3(2048/32, 2048/32), tb, 0, stream>>>(Wo, WoT, 2048, 2048);

    gemm_out<<<dim3(16, 32), 256, 0, stream>>>(Yb, WoT, out);
}

// Round 11
// 333.730 us; speedup vs baseline: 1.0940x; 1.0940x over previous
//
#include <hip/hip_runtime.h>
#include <cstdint>

typedef unsigned short u16;
typedef __attribute__((ext_vector_type(8))) short short8;   // bf16x8 MFMA frag
typedef __attribute__((ext_vector_type(4))) short short4v;  // bf16x4
typedef __attribute__((ext_vector_type(4))) float f32x4;    // fp32x4 accumulator

#define SEQ     2048
#define NHEADS  32
#define NKV     8
#define HD      64
#define DM      2048
#define MROWS   4096   // BATCH * SEQ
#define KVSTR   1024   // fused KV row stride (8 K-heads | 8 V-heads)
#define PSTR    88     // Ps row stride (u16): 176B, 16B-aligned, 2-way banks

__device__ __forceinline__ float b2f(unsigned int u) {
    return __builtin_bit_cast(float, u << 16);
}
__device__ __forceinline__ u16 f2b(float f) {
    unsigned int u = __builtin_bit_cast(unsigned int, f);
    return (u16)((u + 0x7fffu + ((u >> 16) & 1u)) >> 16);   // RNE
}
// packed f32x2 -> bf16x2 (HW RNE). No builtin on gfx950 (m240) — inline asm.
__device__ __forceinline__ unsigned int cvt_pk_bf16(float lo, float hi) {
    unsigned int r;
    asm("v_cvt_pk_bf16_f32 %0, %1, %2" : "=v"(r) : "v"(lo), "v"(hi));
    return r;
}
// ROUND-11: bare v_exp_f32 (2^x). Round 10's exp2f lowered to the PRECISE
// libm path (denormal-fixup sequence, ~6-10 instr) — slower than __expf's
// mul+exp. The raw builtin is 1 instruction; HW handles the full range
// (sub-2^-126 results flush to 0, irrelevant in a softmax sum >= 1).
__device__ __forceinline__ float exp2_raw(float x) {
    return __builtin_amdgcn_exp2f(x);
}

// ---- DPP 16-lane reductions (VALU pipe — round-4 win, keep)
__device__ __forceinline__ float dpp_red_max16(float x) {
    int v = __builtin_bit_cast(int, x);
    x = fmaxf(x, __builtin_bit_cast(float,
        __builtin_amdgcn_update_dpp(v, v, 0xB1, 0xF, 0xF, true)));
    v = __builtin_bit_cast(int, x);
    x = fmaxf(x, __builtin_bit_cast(float,
        __builtin_amdgcn_update_dpp(v, v, 0x4E, 0xF, 0xF, true)));
    v = __builtin_bit_cast(int, x);
    x = fmaxf(x, __builtin_bit_cast(float,
        __builtin_amdgcn_update_dpp(v, v, 0x141, 0xF, 0xF, true)));
    v = __builtin_bit_cast(int, x);
    x = fmaxf(x, __builtin_bit_cast(float,
        __builtin_amdgcn_update_dpp(v, v, 0x140, 0xF, 0xF, true)));
    return x;
}
__device__ __forceinline__ float dpp_red_sum16(float x) {
    int v = __builtin_bit_cast(int, x);
    x = x + __builtin_bit_cast(float,
        __builtin_amdgcn_update_dpp(v, v, 0xB1, 0xF, 0xF, true));
    v = __builtin_bit_cast(int, x);
    x = x + __builtin_bit_cast(float,
        __builtin_amdgcn_update_dpp(v, v, 0x4E, 0xF, 0xF, true));
    v = __builtin_bit_cast(int, x);
    x = x + __builtin_bit_cast(float,
        __builtin_amdgcn_update_dpp(v, v, 0x141, 0xF, 0xF, true));
    v = __builtin_bit_cast(int, x);
    x = x + __builtin_bit_cast(float,
        __builtin_amdgcn_update_dpp(v, v, 0x140, 0xF, 0xF, true));
    return x;
}

// async global->LDS, 16B per lane; LDS dest = WAVE-UNIFORM base + lane*16;
// global source is per-lane (enables source-side swizzle).
#define GLOAD_LDS16(g, l)                                              \
    __builtin_amdgcn_global_load_lds(                                  \
        (const __attribute__((address_space(1))) void*)(g),            \
        (__attribute__((address_space(3))) void*)(l), 16, 0, 0)

// ------------------------------------------------------------- f32 -> bf16
__global__ __launch_bounds__(256) void cvt_f32_bf16(
    const float* __restrict__ in, u16* __restrict__ out, int n4) {
    int i = blockIdx.x * 256 + threadIdx.x;
    if (i < n4) {
        float4 v = ((const float4*)in)[i];
        ushort4 o;
        o.x = f2b(v.x); o.y = f2b(v.y); o.z = f2b(v.z); o.w = f2b(v.w);
        ((ushort4*)out)[i] = o;
    }
}

// ------------------------------------------------------------- RoPE tables
__global__ __launch_bounds__(256) void rope_table_kernel(
    float* __restrict__ cosT, float* __restrict__ sinT) {
    int idx = blockIdx.x * 256 + threadIdx.x;     // 65536 = 2048*32
    int s  = idx >> 5;
    int dl = idx & 31;
    float inv_freq = exp2f((float)dl * -0.41524101186092025f); // 10000^(-dl/32)
    float ang = (float)s * inv_freq;
    float sn, cs;
    sincosf(ang, &sn, &cs);                        // accurate (range-reduced)
    cosT[idx] = cs;
    sinT[idx] = sn;
}

// ------------------------------------------------- transpose + downcast
__global__ __launch_bounds__(256) void transpose_f32_bf16(
    const float* __restrict__ in, u16* __restrict__ out, int K, int N) {
    __shared__ float tile[32][33];
    int n0 = blockIdx.x * 32, k0 = blockIdx.y * 32;
    int tx = threadIdx.x, ty = threadIdx.y;   // 32 x 8
    for (int r = ty; r < 32; r += 8)
        tile[r][tx] = in[(size_t)(k0 + r) * N + n0 + tx];
    __syncthreads();
    for (int r = ty; r < 32; r += 8)
        out[(size_t)(n0 + r) * K + k0 + tx] = f2b(tile[tx][r]);
}

// ------------------------------------------------------- GEMM core macro
// Depth-3 ring, stage AFTER wait+barrier (round-9 proven schedule; the
// round-7/8 stage-before-barrier variant raced: staging tile s+2 writes
// tile s-1's buffer while other waves may still read it). Wait ladder:
// top of step s has tiles s,s+1 outstanding (8 loads) -> vmcnt(4);
// s==NT-1 -> vmcnt(0). Never drains mid-loop. Slot-swizzled LDS for
// conflict-free ds_read_b128 (inverse swizzle pre-applied on per-lane
// GLOBAL source; LDS dest linear). XCD-chunked bijective block swizzle
// (T1); s_setprio around MFMA (T5).
#define GEMM_BODY(Aptr, BTptr, Kdim)                                        \
    __shared__ __align__(16) u16 rA[3][4096];                               \
    __shared__ __align__(16) u16 rB[3][4096];                               \
    const int tid  = threadIdx.x;                                           \
    const int wid  = tid >> 6;                                              \
    const int lane = tid & 63;                                              \
    const int quad = lane >> 4;                                             \
    const int l16  = lane & 15;                                             \
    const int nwg  = gridDim.x * gridDim.y;                                 \
    const int fid  = blockIdx.y * gridDim.x + blockIdx.x;                   \
    const int swz  = (fid & 7) * (nwg >> 3) + (fid >> 3);                   \
    const int rowBase = (swz / gridDim.x) * 128;                            \
    const int colBase = (swz % gridDim.x) * 128;                            \
    const int wr = (wid >> 1) * 64;                                         \
    const int wc = (wid & 1) * 64;                                          \
    size_t sAoff[2], sBoff[2];                                              \
    int ldOff[2];                                                           \
    _Pragma("unroll")                                                       \
    for (int j = 0; j < 2; ++j) {                                           \
        const int p = j * 256 + tid;      /* phys 16B slot this thread fills */ \
        const int q = p >> 3;                                               \
        const int u = (p & 7) ^ (q & 7);  /* inverse swizzle */             \
        const int r = (q << 1) | (u >> 2);                                  \
        const int sc = (u & 3) * 8;       /* k-subgroup (elements) */       \
        sAoff[j] = (size_t)(rowBase + r) * (Kdim) + sc;                     \
        sBoff[j] = (size_t)(colBase + r) * (Kdim) + sc;                     \
        ldOff[j] = (j * 256 + (wid << 6)) * 8;   /* wave-uniform, u16 units */ \
    }                                                                       \
    int aOff[4], bOff[4];                 /* swizzled read offsets (u16) */ \
    _Pragma("unroll")                                                       \
    for (int mi = 0; mi < 4; ++mi) {                                        \
        const int ra = wr + mi * 16 + l16;                                  \
        const int qa = ra >> 1;                                             \
        const int ua = ((ra & 1) << 2) | quad;                              \
        aOff[mi] = (qa * 8 + (ua ^ (qa & 7))) * 8;                          \
        const int rb = wc + mi * 16 + l16;                                  \
        const int qb = rb >> 1;                                             \
        const int ub = ((rb & 1) << 2) | quad;                              \
        bOff[mi] = (qb * 8 + (ub ^ (qb & 7))) * 8;                          \
    }                                                                       \
    f32x4 acc[4][4] = {};                                                   \
    const int NT = (Kdim) / 32;                                             \
    _Pragma("unroll")                                                       \
    for (int st = 0; st < 2; ++st) {      /* prologue: stage tiles 0,1 */   \
        _Pragma("unroll")                                                   \
        for (int j = 0; j < 2; ++j) {                                       \
            GLOAD_LDS16(Aptr  + sAoff[j] + st * 32, &rA[st][ldOff[j]]);     \
            GLOAD_LDS16(BTptr + sBoff[j] + st * 32, &rB[st][ldOff[j]]);     \
        }                                                                   \
    }                                                                       \
    int bs = 0;                           /* s % 3, tracked incrementally */ \
    for (int s = 0; s < NT; ++s) {                                          \
        if (s < NT - 1)                                                     \
            asm volatile("s_waitcnt vmcnt(4)\n\ts_barrier" ::: "memory");   \
        else                                                                \
            asm volatile("s_waitcnt vmcnt(0)\n\ts_barrier" ::: "memory");   \
        const u16* Ab = rA[bs];                                             \
        const u16* Bb = rB[bs];                                             \
        short8 a[4], b[4];                                                  \
        _Pragma("unroll")                                                   \
        for (int mi = 0; mi < 4; ++mi) a[mi] = *(const short8*)&Ab[aOff[mi]]; \
        _Pragma("unroll")                                                   \
        for (int ni = 0; ni < 4; ++ni) b[ni] = *(const short8*)&Bb[bOff[ni]]; \
        if (s + 2 < NT) {                 /* stage s+2 (AFTER barrier) */   \
            const int bi = bs == 0 ? 2 : bs - 1;   /* (s+2)%3 */            \
            const int kk = (s + 2) * 32;                                    \
            _Pragma("unroll")                                               \
            for (int j = 0; j < 2; ++j) {                                   \
                GLOAD_LDS16(Aptr  + sAoff[j] + kk, &rA[bi][ldOff[j]]);      \
                GLOAD_LDS16(BTptr + sBoff[j] + kk, &rB[bi][ldOff[j]]);      \
            }                                                               \
        }                                                                   \
        __builtin_amdgcn_s_setprio(1);                                      \
        _Pragma("unroll")                                                   \
        for (int mi = 0; mi < 4; ++mi)                                      \
            _Pragma("unroll")                                               \
            for (int ni = 0; ni < 4; ++ni)                                  \
                acc[mi][ni] = __builtin_amdgcn_mfma_f32_16x16x32_bf16(      \
                    a[mi], b[ni], acc[mi][ni], 0, 0, 0);                    \
        __builtin_amdgcn_s_setprio(0);                                      \
        bs = bs == 2 ? 0 : bs + 1;                                          \
    }                                                                       \
    const int wRow = rowBase + wr;                                          \
    const int wCol = colBase + wc;

// ------------------------------------------------------- fused QKV GEMM
// Q pre-scale is (1/8)*log2(e) — softmax runs in log2 domain.
__global__ __launch_bounds__(256, 3) void gemm_qkv(
    const u16* __restrict__ A, const u16* __restrict__ BT,
    u16* __restrict__ Qb, u16* __restrict__ KVb,
    const float* __restrict__ cosT, const float* __restrict__ sinT) {
    GEMM_BODY(A, BT, DM)

    u16* dst;
    int dstride, dcol;
    float scale;
    bool doRope;
    if (wCol < 2048)      { dst = Qb;  dstride = 2048; dcol = wCol;
                            scale = 0.18033688011112042f; doRope = true;  } // log2e/8
    else if (wCol < 2560) { dst = KVb; dstride = 1024; dcol = wCol - 2048; scale = 1.0f; doRope = true;  }
    else                  { dst = KVb; dstride = 1024; dcol = wCol - 2048; scale = 1.0f; doRope = false; }

#pragma unroll
    for (int mi = 0; mi < 4; ++mi) {
#pragma unroll
        for (int r = 0; r < 4; ++r) {
            const int R = wRow + mi * 16 + quad * 4 + r;
            u16* crow = dst + (size_t)R * dstride + dcol;
            if (doRope) {
                const int s = R & (SEQ - 1);
#pragma unroll
                for (int ni = 0; ni < 2; ++ni) {
                    const int dl = ni * 16 + l16;           // 0..31
                    float lo = acc[mi][ni][r];
                    float hi = acc[mi][ni + 2][r];
                    float cs = cosT[s * 32 + dl];
                    float sn = sinT[s * 32 + dl];
                    crow[dl]      = f2b((lo * cs - hi * sn) * scale);
                    crow[dl + 32] = f2b((hi * cs + lo * sn) * scale);
                }
            } else {
#pragma unroll
                for (int ni = 0; ni < 4; ++ni)
                    crow[ni * 16 + l16] = f2b(acc[mi][ni][r]);
            }
        }
    }
}

// ------------------------------------------------------- output GEMM (f32)
__global__ __launch_bounds__(256, 3) void gemm_out(
    const u16* __restrict__ A, const u16* __restrict__ BT,
    float* __restrict__ C32) {
    GEMM_BODY(A, BT, DM)
#pragma unroll
    for (int mi = 0; mi < 4; ++mi) {
#pragma unroll
        for (int r = 0; r < 4; ++r) {
            const int R = wRow + mi * 16 + quad * 4 + r;
            float* crow = C32 + (size_t)R * DM + wCol;
#pragma unroll
            for (int ni = 0; ni < 4; ++ni)
                crow[ni * 16 + l16] = acc[mi][ni][r];
        }
    }
}

// ------------------------------------------------------- flash attention
// 4 waves x 32 q-rows/wave (r9) + log2-domain softmax + cvt_pk P-store
// (r10). ROUND-11 FIX: exp via __builtin_amdgcn_exp2f (bare v_exp_f32,
// 1 instr). r10's exp2f lowered to the precise libm path (denormal-fixup,
// ~6-10 instr) — SLOWER than r9's __expf(mul+exp); that was the entire
// 107->123 regression. With the raw builtin, the log2 redesign finally
// nets: exp cost 64->32 instr/wave-tile, P-store ~128->~48.
// Split-K (r3) + DPP softmax (r4) + T13 defer-max retained.
__global__ __launch_bounds__(256, 3) void flash_attn(
    const u16* __restrict__ Q, const u16* __restrict__ KV,
    u16* __restrict__ Yb, float* __restrict__ PoA,
    float* __restrict__ Ml) {
    __shared__ __align__(16) u16 Ks[64 * 64];         // 8 KB, XOR-swizzled
    __shared__ __align__(16) u16 Vt[64 * 72];         // 9 KB, [dim][key]
    __shared__ __align__(16) u16 Ps[4 * 32 * PSTR];   // 22 KB

    const int p   = blockIdx.x >> 1;    // pair 0..7
    const int sh  = blockIdx.x & 1;     // key-half 0/1
    const int h   = blockIdx.y;
    const int b   = blockIdx.z;
    const int kvh = h >> 2;
    const int tid  = threadIdx.x;
    const int wid  = tid >> 6;          // 0..3
    const int lane = tid & 63;
    const int quad = lane >> 4;
    const int l16  = lane & 15;

    const u16* Kg = KV + (size_t)b * SEQ * KVSTR + kvh * HD;
    const u16* Vg = Kg + 512;
    u16* Psw = Ps + wid * 32 * PSTR;

    // staging coords (256 threads)
    const int kKey = tid >> 2;          // key row 0..63
    const int kC0  = (tid & 3) * 2;     // two 16B chunks: kC0, kC0+1
    const int vkp  = tid & 31;          // V key pair 2vkp, 2vkp+1
    const int vd0  = (tid >> 5) * 8;    // 8 dims

    for (int ph = 0; ph < 2; ++ph) {
        const int qt = ph ? (15 - p) : p;
        const int hc = ph ? (16 - p) : (p + 1);   // tiles in each key-half
        const int tS = sh * hc;                    // first key-tile index
        const int rowBaseW = qt * 128 + wid * 32;

        // --- preload Q A-frags (pre-scaled log2e/8), 2 row-tiles x 2 k-slices
        short8 qf[2][2];
#pragma unroll
        for (int rt = 0; rt < 2; ++rt)
#pragma unroll
            for (int ks = 0; ks < 2; ++ks)
                qf[rt][ks] = *(const short8*)&Q[
                    (size_t)(b * SEQ + rowBaseW + rt * 16 + l16) * (NHEADS * HD)
                    + h * HD + ks * 32 + quad * 8];

        f32x4 o[2][4] = {};
        float mi[8], li[8];
#pragma unroll
        for (int i = 0; i < 8; ++i) { mi[i] = -3e38f; li[i] = 0.f; }

        // --- prefetch first tile of this phase's range
        const size_t jF = (size_t)tS * 64;
        short8 kreg0 = *(const short8*)&Kg[(jF + kKey) * KVSTR + kC0 * 8];
        short8 kreg1 = *(const short8*)&Kg[(jF + kKey) * KVSTR + kC0 * 8 + 8];
        short8 vA = *(const short8*)&Vg[(jF + 2 * vkp)     * KVSTR + vd0];
        short8 vB = *(const short8*)&Vg[(jF + 2 * vkp + 1) * KVSTR + vd0];

        for (int tt = 0; tt < hc; ++tt) {
            const int j0 = (tS + tt) * 64;
            __syncthreads();   // previous tile's LDS reads done

            // --- write staged K (XOR-swizzled 16B chunks, 2 per thread)
            *(short8*)&Ks[kKey * 64 + (((kC0)     ^ (kKey & 7)) * 8)] = kreg0;
            *(short8*)&Ks[kKey * 64 + (((kC0 + 1) ^ (kKey & 7)) * 8)] = kreg1;
            // --- write staged V as packed key-pairs (8 x b32, conflict-free)
#pragma unroll
            for (int i = 0; i < 8; ++i) {
                unsigned int w = (unsigned int)(u16)vA[i]
                               | ((unsigned int)(u16)vB[i] << 16);
                ((unsigned int*)Vt)[(vd0 + i) * 36 + vkp] = w;
            }
            __syncthreads();

            // --- prefetch tile tt+1 (overlaps with compute below)
            if (tt + 1 < hc) {
                const size_t jn = (size_t)(j0 + 64);
                kreg0 = *(const short8*)&Kg[(jn + kKey) * KVSTR + kC0 * 8];
                kreg1 = *(const short8*)&Kg[(jn + kKey) * KVSTR + kC0 * 8 + 8];
                vA = *(const short8*)&Vg[(jn + 2 * vkp)     * KVSTR + vd0];
                vB = *(const short8*)&Vg[(jn + 2 * vkp + 1) * KVSTR + vd0];
            }

            // --- S = Q @ K^T (16 MFMA; each bk feeds both row-tiles)
            f32x4 s[2][4] = {};
#pragma unroll
            for (int ks = 0; ks < 2; ++ks)
#pragma unroll
                for (int ct = 0; ct < 4; ++ct) {
                    int key = ct * 16 + l16;
                    int cc  = (ks * 4 + quad) ^ (key & 7);
                    short8 bk = *(const short8*)&Ks[key * 64 + cc * 8];
                    s[0][ct] = __builtin_amdgcn_mfma_f32_16x16x32_bf16(
                        qf[0][ks], bk, s[0][ct], 0, 0, 0);
                    s[1][ct] = __builtin_amdgcn_mfma_f32_16x16x32_bf16(
                        qf[1][ks], bk, s[1][ct], 0, 0, 0);
                }

            // --- causal mask (per row-tile gate)
#pragma unroll
            for (int rt = 0; rt < 2; ++rt) {
                const int rB = rowBaseW + rt * 16;
                if (j0 + 63 > rB) {
#pragma unroll
                    for (int ct = 0; ct < 4; ++ct)
#pragma unroll
                        for (int r = 0; r < 4; ++r) {
                            int R = rB + quad * 4 + r;
                            int J = j0 + ct * 16 + l16;
                            if (J > R) s[rt][ct][r] = -3e38f;
                        }
                }
            }

            // --- online softmax, log2 domain (DPP reduce) + T13 defer-max
#pragma unroll
            for (int rt = 0; rt < 2; ++rt)
#pragma unroll
                for (int r = 0; r < 4; ++r) {
                    const int ix = rt * 4 + r;
                    float rmax = fmaxf(fmaxf(s[rt][0][r], s[rt][1][r]),
                                       fmaxf(s[rt][2][r], s[rt][3][r]));
                    rmax = dpp_red_max16(rmax);
                    if (!__all(rmax <= mi[ix] + 11.54f)) {   // 8 nats in bits
                        float mnew  = fmaxf(mi[ix], rmax);
                        float alpha = exp2_raw(mi[ix] - mnew);
                        mi[ix] = mnew;
                        li[ix] *= alpha;
#pragma unroll
                        for (int ct = 0; ct < 4; ++ct) o[rt][ct][r] *= alpha;
                    }
                    float rs = 0.f;
#pragma unroll
                    for (int ct = 0; ct < 4; ++ct) {
                        float pv = exp2_raw(s[rt][ct][r] - mi[ix]);
                        s[rt][ct][r] = pv;
                        rs += pv;
                    }
                    rs = dpp_red_sum16(rs);
                    li[ix] += rs;
                }

            // --- P -> bf16 via packed cvt, C-layout -> LDS (wave-private)
#pragma unroll
            for (int rt = 0; rt < 2; ++rt)
#pragma unroll
                for (int ct = 0; ct < 4; ++ct)
#pragma unroll
                    for (int rp = 0; rp < 2; ++rp) {
                        unsigned int pk = cvt_pk_bf16(s[rt][ct][2 * rp],
                                                      s[rt][ct][2 * rp + 1]);
                        const int row = rt * 16 + quad * 4 + 2 * rp;
                        Psw[row * PSTR + ct * 16 + l16]       = (u16)pk;
                        Psw[(row + 1) * PSTR + ct * 16 + l16] = (u16)(pk >> 16);
                    }

            // --- O += P @ V (16 MFMA; each vbf feeds both row-tiles)
#pragma unroll
            for (int ks = 0; ks < 2; ++ks) {
                short8 pa0 = *(const short8*)&Psw[l16 * PSTR + ks * 32 + quad * 8];
                short8 pa1 = *(const short8*)&Psw[(16 + l16) * PSTR + ks * 32 + quad * 8];
#pragma unroll
                for (int ct = 0; ct < 4; ++ct) {
                    short8 vbf = *(const short8*)&Vt[(ct * 16 + l16) * 72 + ks * 32 + quad * 8];
                    o[0][ct] = __builtin_amdgcn_mfma_f32_16x16x32_bf16(
                        pa0, vbf, o[0][ct], 0, 0, 0);
                    o[1][ct] = __builtin_amdgcn_mfma_f32_16x16x32_bf16(
                        pa1, vbf, o[1][ct], 0, 0, 0);
                }
            }
        }

        // --- write this phase's normalized partial + (m,l)  [m in log2 units]
        float rli[8];
#pragma unroll
        for (int i = 0; i < 8; ++i)
            rli[i] = li[i] > 0.f ? 1.0f / li[i] : 0.f;   // guard empty rows
        if (sh == 0) {
#pragma unroll
            for (int rt = 0; rt < 2; ++rt)
#pragma unroll
                for (int r = 0; r < 4; ++r) {
                    int R = rowBaseW + rt * 16 + quad * 4 + r;
                    float* arow = PoA + (size_t)(b * SEQ + R) * (NHEADS * HD) + h * HD;
#pragma unroll
                    for (int ct = 0; ct < 4; ++ct)
                        arow[ct * 16 + l16] = o[rt][ct][r] * rli[rt * 4 + r];
                }
        } else {
#pragma unroll
            for (int rt = 0; rt < 2; ++rt)
#pragma unroll
                for (int r = 0; r < 4; ++r) {
                    int R = rowBaseW + rt * 16 + quad * 4 + r;
                    u16* yrow = Yb + (size_t)(b * SEQ + R) * (NHEADS * HD) + h * HD;
#pragma unroll
                    for (int ct = 0; ct < 4; ++ct)
                        yrow[ct * 16 + l16] = f2b(o[rt][ct][r] * rli[rt * 4 + r]);
                }
        }
        if (l16 == 0) {
            float2* MlX = (float2*)Ml + (size_t)sh * 131072
                        + ((b * 32 + h) * 2048 + rowBaseW + quad * 4);
#pragma unroll
            for (int rt = 0; rt < 2; ++rt)
#pragma unroll
                for (int r = 0; r < 4; ++r)
                    MlX[rt * 16 + r] = make_float2(mi[rt * 4 + r], li[rt * 4 + r]);
        }
    }
}

// ------------------------------------------------------- split-K combine
// m-values are in LOG2 domain -> raw v_exp weights.
__global__ __launch_bounds__(256) void combine_kernel(
    const float* __restrict__ PoA, const float* __restrict__ Ml,
    u16* __restrict__ Yb) {
    const size_t e = ((size_t)blockIdx.x * 256 + threadIdx.x) * 8;
    const int rowg = (int)(e >> 11);          // b*2048 + row
    const int c    = (int)(e & 2047);
    const int h    = c >> 6;
    const int bz   = rowg >> 11;
    const int row  = rowg & 2047;
    const int slot = ((bz * 32 + h) * 2048 + row) * 2;
    const float mA = Ml[slot],          lA = Ml[slot + 1];
    const float mB = Ml[262144 + slot], lB = Ml[262144 + slot + 1];
    const float m  = fmaxf(mA, mB);
    const float wA = lA * __builtin_amdgcn_exp2f(mA - m);
    const float wB = lB * __builtin_amdgcn_exp2f(mB - m);
    const float inv = 1.0f / (wA + wB);       // lA > 0 always
    const float a = wA * inv, bw = wB * inv;
    float4 A0 = *(const float4*)(PoA + e);
    float4 A1 = *(const float4*)(PoA + e + 4);
    short8 Bv = *(const short8*)(Yb + e);
    float av[8] = {A0.x, A0.y, A0.z, A0.w, A1.x, A1.y, A1.z, A1.w};
    u16 yo[8];
#pragma unroll
    for (int j = 0; j < 8; ++j)
        yo[j] = f2b(a * av[j] + bw * b2f((unsigned int)(u16)Bv[j]));
    *(short8*)(Yb + e) = *(short8*)yo;
}

// ---------------------------------------------------------------- launch
extern "C" void kernel_launch(void* const* d_in, const int* in_sizes, int n_in,
                              void* d_out, int out_size, void* d_ws, size_t ws_size,
                              hipStream_t stream) {
    const float* x  = (const float*)d_in[0];
    const float* Wq = (const float*)d_in[1];
    const float* Wk = (const float*)d_in[2];
    const float* Wv = (const float*)d_in[3];
    const float* Wo = (const float*)d_in[4];
    float* out = (float*)d_out;   // f32 output

    char* ws = (char*)d_ws;
    u16*  xb    = (u16*)(ws);                    // 16 MB  4096x2048 bf16
    u16*  WqkvT = (u16*)(ws + 16777216);         // 12 MB  3072x2048 (Wq|Wk|Wv)^T
    u16*  WoT   = (u16*)(ws + 29360128);         //  8 MB  2048x2048 [28,36) MB
    u16*  Qb    = (u16*)(ws + 37748736);         // 16 MB  (roped, pre-scaled log2e/8)
    u16*  KVb   = (u16*)(ws + 54525952);         //  8 MB  4096x1024 (K roped | V)
    u16*  Yb    = (u16*)(ws + 62914560);         // 16 MB  partial-B then final Y
    float* cosT = (float*)(ws + 79691776);       // 256 KB
    float* sinT = (float*)(ws + 79953920);       // 256 KB
    // flash-phase aliases (xb/WqkvT/WoT dead during attention):
    float* PoA  = (float*)(ws);                  // 32 MB f32 partial-A [0,32)
    float* Ml   = (float*)(ws + 33554432);       //  2 MB (m,l) x {A,B} [32,34)

    rope_table_kernel<<<dim3(65536 / 256), 256, 0, stream>>>(cosT, sinT);

    cvt_f32_bf16<<<dim3(MROWS * DM / 4 / 256), 256, 0, stream>>>(x, xb, MROWS * DM / 4);

    dim3 tb(32, 8);
    transpose_f32_bf16<<<dim3(2048/32, 2048/32), tb, 0, stream>>>(Wq, WqkvT, 2048, 2048);
    transpose_f32_bf16<<<dim3( 512/32, 2048/32), tb, 0, stream>>>(Wk, WqkvT + 2048 * 2048, 2048, 512);
    transpose_f32_bf16<<<dim3( 512/32, 2048/32), tb, 0, stream>>>(Wv, WqkvT + 2560 * 2048, 2048, 512);

    gemm_qkv<<<dim3(24, 32), 256, 0, stream>>>(xb, WqkvT, Qb, KVb, cosT, sinT);

    flash_attn<<<dim3(16, NHEADS, 2), 256, 0, stream>>>(Qb, KVb, Yb, PoA, Ml);

    combine_kernel<<<dim3(4096), 256, 0, stream>>>(PoA, Ml, Yb);

    // Wo transpose AFTER combine: WoT region [28,36) was reused for
    // PoA-tail + Ml during the attention phase (stream is serial).
    transpose_f32_bf16<<<dim3(2048/32, 2048/32), tb, 0, stream>>>(Wo, WoT, 2048, 2048);

    gemm_out<<<dim3(16, 32), 256, 0, stream>>>(Yb, WoT, out);
}